// Round 17
// baseline (199.279 us; speedup 1.0000x reference)
//
#include <hip/hip_runtime.h>
#include <hip/hip_bf16.h>

#define F_IN 512
#define NCLS 64
#define SCAN_BLK 512
#define CNT_STRIDE 16  // one counter per 64B line

typedef __attribute__((ext_vector_type(8))) short short8;
typedef __attribute__((ext_vector_type(4))) float f32x4;

static __device__ __forceinline__ short bf16_of(float f) {
    __hip_bfloat16 h = __float2bfloat16(f);
    short s;
    __builtin_memcpy(&s, &h, 2);
    return s;
}
static __device__ __forceinline__ float b2f(short s) {
    unsigned u = ((unsigned)(unsigned short)s) << 16;
    float f;
    __builtin_memcpy(&f, &u, 4);
    return f;
}

// ---------------- prelude: wconvert (blocks 0..15) + zero padded cnt (rest) ----------------
__global__ __launch_bounds__(256) void k_prelude(const float* __restrict__ W,
                                                 short* __restrict__ Wb,
                                                 int* __restrict__ cnt, int nWords) {
    const int bid = blockIdx.x;
    if (bid < 16) {
        int t = bid * 256 + threadIdx.x;  // 4096 total
        int c = t >> 10;
        int kk = (t >> 6) & 15;
        int l = t & 63;
        short8 v;
#pragma unroll
        for (int j = 0; j < 8; ++j) {
            v[j] = bf16_of(W[(size_t)(kk * 32 + (l >> 4) * 8 + j) * NCLS + c * 16 + (l & 15)]);
        }
        reinterpret_cast<short8*>(Wb)[t] = v;
    } else {
        int i = ((bid - 16) * 256 + threadIdx.x) * 4;
        if (i + 4 <= nWords) {
            *reinterpret_cast<int4*>(cnt + i) = make_int4(0, 0, 0, 0);
        } else {
            for (int k2 = i; k2 < nWords; ++k2) cnt[k2] = 0;
        }
    }
}

// ---------------- deg_count: 8 edges/thread, returning atomics on line-padded counters ----------------
__global__ __launch_bounds__(256) void k_deg(const int* __restrict__ dst,
                                             int* __restrict__ cnt,
                                             unsigned char* __restrict__ rank, int e) {
    int base = (blockIdx.x * 256 + threadIdx.x) * 8;
    if (base + 8 <= e) {
        int4 dA = *reinterpret_cast<const int4*>(dst + base);
        int4 dB = *reinterpret_cast<const int4*>(dst + base + 4);
        uchar4 rA, rB;
        rA.x = (unsigned char)atomicAdd(&cnt[dA.x * CNT_STRIDE], 1);
        rA.y = (unsigned char)atomicAdd(&cnt[dA.y * CNT_STRIDE], 1);
        rA.z = (unsigned char)atomicAdd(&cnt[dA.z * CNT_STRIDE], 1);
        rA.w = (unsigned char)atomicAdd(&cnt[dA.w * CNT_STRIDE], 1);
        rB.x = (unsigned char)atomicAdd(&cnt[dB.x * CNT_STRIDE], 1);
        rB.y = (unsigned char)atomicAdd(&cnt[dB.y * CNT_STRIDE], 1);
        rB.z = (unsigned char)atomicAdd(&cnt[dB.z * CNT_STRIDE], 1);
        rB.w = (unsigned char)atomicAdd(&cnt[dB.w * CNT_STRIDE], 1);
        *reinterpret_cast<uchar4*>(rank + base) = rA;
        *reinterpret_cast<uchar4*>(rank + base + 4) = rB;
    } else {
        for (int i = base; i < e; ++i)
            rank[i] = (unsigned char)atomicAdd(&cnt[dst[i] * CNT_STRIDE], 1);
    }
}

// ---------------- scan1: block-local exclusive scan + dinv; off[n] sentinel ----------------
__global__ __launch_bounds__(SCAN_BLK) void k_scan1(const int* __restrict__ cnt,
                                                    int* __restrict__ off,
                                                    int* __restrict__ partials,
                                                    float* __restrict__ dinv, int n) {
    __shared__ int s[SCAN_BLK];
    int tid = threadIdx.x;
    int i = blockIdx.x * SCAN_BLK + tid;
    int v = (i < n) ? cnt[i * CNT_STRIDE] : 0;
    if (i < n) dinv[i] = rsqrtf(1.0f + (float)v);
    s[tid] = v;
    __syncthreads();
#pragma unroll
    for (int d = 1; d < SCAN_BLK; d <<= 1) {
        int t = (tid >= d) ? s[tid - d] : 0;
        __syncthreads();
        s[tid] += t;
        __syncthreads();
    }
    if (i < n) off[i] = s[tid] - v;       // block-local exclusive
    if (i == n - 1) off[n] = s[tid];      // block-local inclusive sentinel
    if (tid == SCAN_BLK - 1) partials[blockIdx.x] = s[tid];
}

__global__ __launch_bounds__(256) void k_scan2(int* __restrict__ partials, int p) {
    __shared__ int s[256];
    int tid = threadIdx.x;
    int v = (tid < p) ? partials[tid] : 0;
    s[tid] = v;
    __syncthreads();
#pragma unroll
    for (int d = 1; d < 256; d <<= 1) {
        int t = (tid >= d) ? s[tid - d] : 0;
        __syncthreads();
        s[tid] += t;
        __syncthreads();
    }
    if (tid < p) partials[tid] = s[tid] - v;  // exclusive
}

// ---------------- fill CSR — NO atomics, 4 edges/thread ----------------
__global__ __launch_bounds__(256) void k_fill(const int* __restrict__ src,
                                              const int* __restrict__ dst,
                                              const int* __restrict__ off,
                                              const int* __restrict__ parts,
                                              const unsigned char* __restrict__ rank,
                                              int* __restrict__ eidx, int e) {
    int base = (blockIdx.x * 256 + threadIdx.x) * 4;
    if (base + 4 <= e) {
        int4 s4 = *reinterpret_cast<const int4*>(src + base);
        int4 d4 = *reinterpret_cast<const int4*>(dst + base);
        uchar4 r4 = *reinterpret_cast<const uchar4*>(rank + base);
        eidx[off[d4.x] + parts[d4.x >> 9] + r4.x] = s4.x;
        eidx[off[d4.y] + parts[d4.y >> 9] + r4.y] = s4.y;
        eidx[off[d4.z] + parts[d4.z >> 9] + r4.z] = s4.z;
        eidx[off[d4.w] + parts[d4.w >> 9] + r4.w] = s4.w;
    } else {
        for (int i = base; i < e; ++i)
            eidx[off[dst[i]] + parts[dst[i] >> 9] + rank[i]] = src[i];
    }
}

// ---------------- MFMA GEMM: g = bf16((x @ W) * dinv[row]), 32 rows/wave ----------------
__global__ __launch_bounds__(256) void k_gemm(const float* __restrict__ x,
                                              const short* __restrict__ Wb,
                                              const float* __restrict__ dinv,
                                              short* __restrict__ g, int n) {
    const int wave = threadIdx.x >> 6;
    const int lane = threadIdx.x & 63;
    const int rowTile = blockIdx.x * 128 + wave * 32;

    int r0 = rowTile + (lane & 15);
    int r1 = r0 + 16;
    if (r0 > n - 1) r0 = n - 1;
    if (r1 > n - 1) r1 = n - 1;
    const float* xr0 = x + (size_t)r0 * F_IN + ((lane >> 4) * 8);
    const float* xr1 = x + (size_t)r1 * F_IN + ((lane >> 4) * 8);

    const short8* wb8 = reinterpret_cast<const short8*>(Wb);

    f32x4 acc[2][4];
#pragma unroll
    for (int h = 0; h < 2; ++h)
#pragma unroll
        for (int c = 0; c < 4; ++c) acc[h][c] = {0.f, 0.f, 0.f, 0.f};

#pragma unroll 4
    for (int kk = 0; kk < 16; ++kk) {
        float4 p0 = *reinterpret_cast<const float4*>(xr0 + kk * 32);
        float4 p1 = *reinterpret_cast<const float4*>(xr0 + kk * 32 + 4);
        float4 q0 = *reinterpret_cast<const float4*>(xr1 + kk * 32);
        float4 q1 = *reinterpret_cast<const float4*>(xr1 + kk * 32 + 4);
        short8 a0, a1;
        a0[0] = bf16_of(p0.x); a0[1] = bf16_of(p0.y);
        a0[2] = bf16_of(p0.z); a0[3] = bf16_of(p0.w);
        a0[4] = bf16_of(p1.x); a0[5] = bf16_of(p1.y);
        a0[6] = bf16_of(p1.z); a0[7] = bf16_of(p1.w);
        a1[0] = bf16_of(q0.x); a1[1] = bf16_of(q0.y);
        a1[2] = bf16_of(q0.z); a1[3] = bf16_of(q0.w);
        a1[4] = bf16_of(q1.x); a1[5] = bf16_of(q1.y);
        a1[6] = bf16_of(q1.z); a1[7] = bf16_of(q1.w);
        short8 b0 = wb8[(0 * 16 + kk) * 64 + lane];
        short8 b1 = wb8[(1 * 16 + kk) * 64 + lane];
        short8 b2 = wb8[(2 * 16 + kk) * 64 + lane];
        short8 b3 = wb8[(3 * 16 + kk) * 64 + lane];
        acc[0][0] = __builtin_amdgcn_mfma_f32_16x16x32_bf16(a0, b0, acc[0][0], 0, 0, 0);
        acc[0][1] = __builtin_amdgcn_mfma_f32_16x16x32_bf16(a0, b1, acc[0][1], 0, 0, 0);
        acc[0][2] = __builtin_amdgcn_mfma_f32_16x16x32_bf16(a0, b2, acc[0][2], 0, 0, 0);
        acc[0][3] = __builtin_amdgcn_mfma_f32_16x16x32_bf16(a0, b3, acc[0][3], 0, 0, 0);
        acc[1][0] = __builtin_amdgcn_mfma_f32_16x16x32_bf16(a1, b0, acc[1][0], 0, 0, 0);
        acc[1][1] = __builtin_amdgcn_mfma_f32_16x16x32_bf16(a1, b1, acc[1][1], 0, 0, 0);
        acc[1][2] = __builtin_amdgcn_mfma_f32_16x16x32_bf16(a1, b2, acc[1][2], 0, 0, 0);
        acc[1][3] = __builtin_amdgcn_mfma_f32_16x16x32_bf16(a1, b3, acc[1][3], 0, 0, 0);
    }

    const int col = lane & 15;
#pragma unroll
    for (int h = 0; h < 2; ++h) {
        const int rbase = rowTile + h * 16 + (lane >> 4) * 4;
#pragma unroll
        for (int j = 0; j < 4; ++j) {
            int r = rbase + j;
            if (r < n) {
                float dv = dinv[r];
                short* go = g + (size_t)r * NCLS + col;
                go[0]  = bf16_of(acc[h][0][j] * dv);
                go[16] = bf16_of(acc[h][1][j] * dv);
                go[32] = bf16_of(acc[h][2][j] * dv);
                go[48] = bf16_of(acc[h][3][j] * dv);
            }
        }
    }
}

// ---------------- fused gather + bias + log_softmax (g pre-scaled by dinv[src]) ----------------
// 8 nodes per wave: 8-lane sub-group per node; lane handles 8 channels (short8 = 16B).
__global__ __launch_bounds__(256) void k_agg(const short* __restrict__ g,
                                             const float* __restrict__ dinv,
                                             const float* __restrict__ bvec,
                                             const int* __restrict__ off,
                                             const int* __restrict__ parts,
                                             const int* __restrict__ eidx,
                                             float* __restrict__ out, int n) {
    const int wave = threadIdx.x >> 6;
    const int lane = threadIdx.x & 63;
    const int grp = lane >> 3;   // node sub-group 0..7
    const int li = lane & 7;     // channels li*8 .. li*8+7
    const int node = (blockIdx.x * 4 + wave) * 8 + grp;
    if (node >= n) return;

    const int s0 = off[node] + parts[node >> 9];
    const int np1 = node + 1;
    const int s1 = off[np1] + parts[(np1 == n ? n - 1 : np1) >> 9];

    const short8* g8 = reinterpret_cast<const short8*>(g);  // 8 short8 per row

    float acc[8];
    {
        short8 v = g8[(size_t)node * 8 + li];
#pragma unroll
        for (int c = 0; c < 8; ++c) acc[c] = b2f(v[c]);
    }

    int t = s0;
    for (; t + 8 <= s1; t += 8) {
        int sidx[8];
#pragma unroll
        for (int u = 0; u < 8; ++u) sidx[u] = eidx[t + u];
        short8 vv[8];
#pragma unroll
        for (int u = 0; u < 8; ++u) vv[u] = g8[(size_t)sidx[u] * 8 + li];
#pragma unroll
        for (int c = 0; c < 8; ++c)
            acc[c] += ((b2f(vv[0][c]) + b2f(vv[1][c])) + (b2f(vv[2][c]) + b2f(vv[3][c]))) +
                      ((b2f(vv[4][c]) + b2f(vv[5][c])) + (b2f(vv[6][c]) + b2f(vv[7][c])));
    }
    for (; t + 4 <= s1; t += 4) {
        int sa = eidx[t], sb = eidx[t + 1], sc = eidx[t + 2], sd = eidx[t + 3];
        short8 va = g8[(size_t)sa * 8 + li];
        short8 vb = g8[(size_t)sb * 8 + li];
        short8 vc = g8[(size_t)sc * 8 + li];
        short8 vd = g8[(size_t)sd * 8 + li];
#pragma unroll
        for (int c = 0; c < 8; ++c)
            acc[c] += (b2f(va[c]) + b2f(vb[c])) + (b2f(vc[c]) + b2f(vd[c]));
    }
    for (; t < s1; ++t) {
        int sa = eidx[t];
        short8 va = g8[(size_t)sa * 8 + li];
#pragma unroll
        for (int c = 0; c < 8; ++c) acc[c] += b2f(va[c]);
    }

    const float dn = dinv[node];
    const float4 b0 = reinterpret_cast<const float4*>(bvec)[li * 2];
    const float4 b1 = reinterpret_cast<const float4*>(bvec)[li * 2 + 1];
    float v[8];
    v[0] = acc[0] * dn + b0.x; v[1] = acc[1] * dn + b0.y;
    v[2] = acc[2] * dn + b0.z; v[3] = acc[3] * dn + b0.w;
    v[4] = acc[4] * dn + b1.x; v[5] = acc[5] * dn + b1.y;
    v[6] = acc[6] * dn + b1.z; v[7] = acc[7] * dn + b1.w;

    float m = v[0];
#pragma unroll
    for (int c = 1; c < 8; ++c) m = fmaxf(m, v[c]);
#pragma unroll
    for (int o = 1; o < 8; o <<= 1) m = fmaxf(m, __shfl_xor(m, o));

    float ex = 0.f;
#pragma unroll
    for (int c = 0; c < 8; ++c) ex += __expf(v[c] - m);
#pragma unroll
    for (int o = 1; o < 8; o <<= 1) ex += __shfl_xor(ex, o);
    const float lg = m + __logf(ex);

    float4 r0, r1;
    r0.x = v[0] - lg; r0.y = v[1] - lg; r0.z = v[2] - lg; r0.w = v[3] - lg;
    r1.x = v[4] - lg; r1.y = v[5] - lg; r1.z = v[6] - lg; r1.w = v[7] - lg;
    float4* o4 = reinterpret_cast<float4*>(out + (size_t)node * NCLS);
    o4[li * 2] = r0;
    o4[li * 2 + 1] = r1;
}

extern "C" void kernel_launch(void* const* d_in, const int* in_sizes, int n_in,
                              void* d_out, int out_size, void* d_ws, size_t ws_size,
                              hipStream_t stream) {
    const float* x = (const float*)d_in[0];       // [N, 512]
    const float* W = (const float*)d_in[1];       // [512, 64]
    const float* b = (const float*)d_in[2];       // [64]
    const int* edge_index = (const int*)d_in[3];  // [2, E]

    const int N = in_sizes[0] / F_IN;
    const int E = in_sizes[3] / 2;
    const int* src = edge_index;
    const int* dst = edge_index + E;

    float* out = (float*)d_out;  // [N, 64]

    // workspace layout (16B-aligned pieces first)
    char* ws = (char*)d_ws;
    short* g     = (short*)ws;  ws += (size_t)N * NCLS * 2;          // 12.8 MB bf16
    short* Wb    = (short*)ws;  ws += 4096 * 16;                     // 64 KB
    float* dinv  = (float*)ws;  ws += (size_t)N * 4;
    int*   cnt   = (int*)ws;    ws += (size_t)N * CNT_STRIDE * 4;    // 6.4 MB line-padded
    int*   off   = (int*)ws;    ws += (size_t)(N + 4) * 4;
    int*   parts = (int*)ws;    ws += 1024 * 4;
    unsigned char* rank = (unsigned char*)ws;  ws += (size_t)((E + 15) & ~15); // 1.6 MB
    int*   eidx  = (int*)ws;    // E ints

    const int nWords = N * CNT_STRIDE;
    const int nScanBlocks = (N + SCAN_BLK - 1) / SCAN_BLK;
    const int fillBlocks = (E + 1023) / 1024;
    const int degBlocks = (E + 2047) / 2048;

    k_prelude<<<16 + (nWords / 4 + 255) / 256, 256, 0, stream>>>(W, Wb, cnt, nWords);

    k_deg<<<degBlocks, 256, 0, stream>>>(dst, cnt, rank, E);

    k_scan1<<<nScanBlocks, SCAN_BLK, 0, stream>>>(cnt, off, parts, dinv, N);
    k_scan2<<<1, 256, 0, stream>>>(parts, nScanBlocks);

    k_gemm<<<(N + 127) / 128, 256, 0, stream>>>(x, Wb, dinv, g, N);

    k_fill<<<fillBlocks, 256, 0, stream>>>(src, dst, off, parts, rank, eidx, E);

    k_agg<<<(N + 31) / 32, 256, 0, stream>>>(g, dinv, b, off, parts, eidx, out, N);
}

// Round 18
// 187.270 us; speedup vs baseline: 1.0641x; 1.0641x over previous
//
#include <hip/hip_runtime.h>
#include <hip/hip_bf16.h>

#define F_IN 512
#define NCLS 64
#define SCAN_BLK 512
#define CNT_STRIDE 16  // one counter per 64B line

typedef __attribute__((ext_vector_type(8))) short short8;
typedef __attribute__((ext_vector_type(4))) float f32x4;

static __device__ __forceinline__ short bf16_of(float f) {
    __hip_bfloat16 h = __float2bfloat16(f);
    short s;
    __builtin_memcpy(&s, &h, 2);
    return s;
}
static __device__ __forceinline__ float b2f(short s) {
    unsigned u = ((unsigned)(unsigned short)s) << 16;
    float f;
    __builtin_memcpy(&f, &u, 4);
    return f;
}

// ---------------- prelude: wconvert (blocks 0..15) + zero padded cnt (rest) ----------------
__global__ __launch_bounds__(256) void k_prelude(const float* __restrict__ W,
                                                 short* __restrict__ Wb,
                                                 int* __restrict__ cnt, int nWords) {
    const int bid = blockIdx.x;
    if (bid < 16) {
        int t = bid * 256 + threadIdx.x;  // 4096 total
        int c = t >> 10;
        int kk = (t >> 6) & 15;
        int l = t & 63;
        short8 v;
#pragma unroll
        for (int j = 0; j < 8; ++j) {
            v[j] = bf16_of(W[(size_t)(kk * 32 + (l >> 4) * 8 + j) * NCLS + c * 16 + (l & 15)]);
        }
        reinterpret_cast<short8*>(Wb)[t] = v;
    } else {
        int i = ((bid - 16) * 256 + threadIdx.x) * 4;
        if (i + 4 <= nWords) {
            *reinterpret_cast<int4*>(cnt + i) = make_int4(0, 0, 0, 0);
        } else {
            for (int k2 = i; k2 < nWords; ++k2) cnt[k2] = 0;
        }
    }
}

// ---------------- deg_count: 8 edges/thread, returning atomics on line-padded counters ----------------
__global__ __launch_bounds__(256) void k_deg(const int* __restrict__ dst,
                                             int* __restrict__ cnt,
                                             unsigned short* __restrict__ rank, int e) {
    int base = (blockIdx.x * 256 + threadIdx.x) * 8;
    if (base + 8 <= e) {
        int4 dA = *reinterpret_cast<const int4*>(dst + base);
        int4 dB = *reinterpret_cast<const int4*>(dst + base + 4);
        ushort4 rA, rB;
        rA.x = (unsigned short)atomicAdd(&cnt[dA.x * CNT_STRIDE], 1);
        rA.y = (unsigned short)atomicAdd(&cnt[dA.y * CNT_STRIDE], 1);
        rA.z = (unsigned short)atomicAdd(&cnt[dA.z * CNT_STRIDE], 1);
        rA.w = (unsigned short)atomicAdd(&cnt[dA.w * CNT_STRIDE], 1);
        rB.x = (unsigned short)atomicAdd(&cnt[dB.x * CNT_STRIDE], 1);
        rB.y = (unsigned short)atomicAdd(&cnt[dB.y * CNT_STRIDE], 1);
        rB.z = (unsigned short)atomicAdd(&cnt[dB.z * CNT_STRIDE], 1);
        rB.w = (unsigned short)atomicAdd(&cnt[dB.w * CNT_STRIDE], 1);
        *reinterpret_cast<ushort4*>(rank + base) = rA;
        *reinterpret_cast<ushort4*>(rank + base + 4) = rB;
    } else {
        for (int i = base; i < e; ++i)
            rank[i] = (unsigned short)atomicAdd(&cnt[dst[i] * CNT_STRIDE], 1);
    }
}

// ---------------- scan1: block-local exclusive scan + dinv; off[n] sentinel ----------------
__global__ __launch_bounds__(SCAN_BLK) void k_scan1(const int* __restrict__ cnt,
                                                    int* __restrict__ off,
                                                    int* __restrict__ partials,
                                                    float* __restrict__ dinv, int n) {
    __shared__ int s[SCAN_BLK];
    int tid = threadIdx.x;
    int i = blockIdx.x * SCAN_BLK + tid;
    int v = (i < n) ? cnt[i * CNT_STRIDE] : 0;
    if (i < n) dinv[i] = rsqrtf(1.0f + (float)v);
    s[tid] = v;
    __syncthreads();
#pragma unroll
    for (int d = 1; d < SCAN_BLK; d <<= 1) {
        int t = (tid >= d) ? s[tid - d] : 0;
        __syncthreads();
        s[tid] += t;
        __syncthreads();
    }
    if (i < n) off[i] = s[tid] - v;       // block-local exclusive
    if (i == n - 1) off[n] = s[tid];      // block-local inclusive sentinel
    if (tid == SCAN_BLK - 1) partials[blockIdx.x] = s[tid];
}

__global__ __launch_bounds__(256) void k_scan2(int* __restrict__ partials, int p) {
    __shared__ int s[256];
    int tid = threadIdx.x;
    int v = (tid < p) ? partials[tid] : 0;
    s[tid] = v;
    __syncthreads();
#pragma unroll
    for (int d = 1; d < 256; d <<= 1) {
        int t = (tid >= d) ? s[tid - d] : 0;
        __syncthreads();
        s[tid] += t;
        __syncthreads();
    }
    if (tid < p) partials[tid] = s[tid] - v;  // exclusive
}

// ---------------- fill CSR — NO atomics, 4 edges/thread ----------------
__global__ __launch_bounds__(256) void k_fill(const int* __restrict__ src,
                                              const int* __restrict__ dst,
                                              const int* __restrict__ off,
                                              const int* __restrict__ parts,
                                              const unsigned short* __restrict__ rank,
                                              int* __restrict__ eidx, int e) {
    int base = (blockIdx.x * 256 + threadIdx.x) * 4;
    if (base + 4 <= e) {
        int4 s4 = *reinterpret_cast<const int4*>(src + base);
        int4 d4 = *reinterpret_cast<const int4*>(dst + base);
        ushort4 r4 = *reinterpret_cast<const ushort4*>(rank + base);
        eidx[off[d4.x] + parts[d4.x >> 9] + r4.x] = s4.x;
        eidx[off[d4.y] + parts[d4.y >> 9] + r4.y] = s4.y;
        eidx[off[d4.z] + parts[d4.z >> 9] + r4.z] = s4.z;
        eidx[off[d4.w] + parts[d4.w >> 9] + r4.w] = s4.w;
    } else {
        for (int i = base; i < e; ++i)
            eidx[off[dst[i]] + parts[dst[i] >> 9] + rank[i]] = src[i];
    }
}

// ---------------- MFMA GEMM: g = bf16((x @ W) * dinv[row]), 32 rows/wave ----------------
__global__ __launch_bounds__(256) void k_gemm(const float* __restrict__ x,
                                              const short* __restrict__ Wb,
                                              const float* __restrict__ dinv,
                                              short* __restrict__ g, int n) {
    const int wave = threadIdx.x >> 6;
    const int lane = threadIdx.x & 63;
    const int rowTile = blockIdx.x * 128 + wave * 32;

    int r0 = rowTile + (lane & 15);
    int r1 = r0 + 16;
    if (r0 > n - 1) r0 = n - 1;
    if (r1 > n - 1) r1 = n - 1;
    const float* xr0 = x + (size_t)r0 * F_IN + ((lane >> 4) * 8);
    const float* xr1 = x + (size_t)r1 * F_IN + ((lane >> 4) * 8);

    const short8* wb8 = reinterpret_cast<const short8*>(Wb);

    f32x4 acc[2][4];
#pragma unroll
    for (int h = 0; h < 2; ++h)
#pragma unroll
        for (int c = 0; c < 4; ++c) acc[h][c] = {0.f, 0.f, 0.f, 0.f};

#pragma unroll 4
    for (int kk = 0; kk < 16; ++kk) {
        float4 p0 = *reinterpret_cast<const float4*>(xr0 + kk * 32);
        float4 p1 = *reinterpret_cast<const float4*>(xr0 + kk * 32 + 4);
        float4 q0 = *reinterpret_cast<const float4*>(xr1 + kk * 32);
        float4 q1 = *reinterpret_cast<const float4*>(xr1 + kk * 32 + 4);
        short8 a0, a1;
        a0[0] = bf16_of(p0.x); a0[1] = bf16_of(p0.y);
        a0[2] = bf16_of(p0.z); a0[3] = bf16_of(p0.w);
        a0[4] = bf16_of(p1.x); a0[5] = bf16_of(p1.y);
        a0[6] = bf16_of(p1.z); a0[7] = bf16_of(p1.w);
        a1[0] = bf16_of(q0.x); a1[1] = bf16_of(q0.y);
        a1[2] = bf16_of(q0.z); a1[3] = bf16_of(q0.w);
        a1[4] = bf16_of(q1.x); a1[5] = bf16_of(q1.y);
        a1[6] = bf16_of(q1.z); a1[7] = bf16_of(q1.w);
        short8 b0 = wb8[(0 * 16 + kk) * 64 + lane];
        short8 b1 = wb8[(1 * 16 + kk) * 64 + lane];
        short8 b2 = wb8[(2 * 16 + kk) * 64 + lane];
        short8 b3 = wb8[(3 * 16 + kk) * 64 + lane];
        acc[0][0] = __builtin_amdgcn_mfma_f32_16x16x32_bf16(a0, b0, acc[0][0], 0, 0, 0);
        acc[0][1] = __builtin_amdgcn_mfma_f32_16x16x32_bf16(a0, b1, acc[0][1], 0, 0, 0);
        acc[0][2] = __builtin_amdgcn_mfma_f32_16x16x32_bf16(a0, b2, acc[0][2], 0, 0, 0);
        acc[0][3] = __builtin_amdgcn_mfma_f32_16x16x32_bf16(a0, b3, acc[0][3], 0, 0, 0);
        acc[1][0] = __builtin_amdgcn_mfma_f32_16x16x32_bf16(a1, b0, acc[1][0], 0, 0, 0);
        acc[1][1] = __builtin_amdgcn_mfma_f32_16x16x32_bf16(a1, b1, acc[1][1], 0, 0, 0);
        acc[1][2] = __builtin_amdgcn_mfma_f32_16x16x32_bf16(a1, b2, acc[1][2], 0, 0, 0);
        acc[1][3] = __builtin_amdgcn_mfma_f32_16x16x32_bf16(a1, b3, acc[1][3], 0, 0, 0);
    }

    const int col = lane & 15;
#pragma unroll
    for (int h = 0; h < 2; ++h) {
        const int rbase = rowTile + h * 16 + (lane >> 4) * 4;
#pragma unroll
        for (int j = 0; j < 4; ++j) {
            int r = rbase + j;
            if (r < n) {
                float dv = dinv[r];
                short* go = g + (size_t)r * NCLS + col;
                go[0]  = bf16_of(acc[h][0][j] * dv);
                go[16] = bf16_of(acc[h][1][j] * dv);
                go[32] = bf16_of(acc[h][2][j] * dv);
                go[48] = bf16_of(acc[h][3][j] * dv);
            }
        }
    }
}

// ---------------- fused gather + bias + log_softmax (g pre-scaled by dinv[src]) ----------------
// 8 nodes per wave: 8-lane sub-group per node; lane handles 8 channels (short8 = 16B).
__global__ __launch_bounds__(256) void k_agg(const short* __restrict__ g,
                                             const float* __restrict__ dinv,
                                             const float* __restrict__ bvec,
                                             const int* __restrict__ off,
                                             const int* __restrict__ parts,
                                             const int* __restrict__ eidx,
                                             float* __restrict__ out, int n) {
    const int wave = threadIdx.x >> 6;
    const int lane = threadIdx.x & 63;
    const int grp = lane >> 3;   // node sub-group 0..7
    const int li = lane & 7;     // channels li*8 .. li*8+7
    const int node = (blockIdx.x * 4 + wave) * 8 + grp;
    if (node >= n) return;

    const int s0 = off[node] + parts[node >> 9];
    const int np1 = node + 1;
    const int s1 = off[np1] + parts[(np1 == n ? n - 1 : np1) >> 9];

    const short8* g8 = reinterpret_cast<const short8*>(g);  // 8 short8 per row

    float acc[8];
    {
        short8 v = g8[(size_t)node * 8 + li];
#pragma unroll
        for (int c = 0; c < 8; ++c) acc[c] = b2f(v[c]);
    }

    int t = s0;
    for (; t + 8 <= s1; t += 8) {
        int sidx[8];
#pragma unroll
        for (int u = 0; u < 8; ++u) sidx[u] = eidx[t + u];
        short8 vv[8];
#pragma unroll
        for (int u = 0; u < 8; ++u) vv[u] = g8[(size_t)sidx[u] * 8 + li];
#pragma unroll
        for (int c = 0; c < 8; ++c)
            acc[c] += ((b2f(vv[0][c]) + b2f(vv[1][c])) + (b2f(vv[2][c]) + b2f(vv[3][c]))) +
                      ((b2f(vv[4][c]) + b2f(vv[5][c])) + (b2f(vv[6][c]) + b2f(vv[7][c])));
    }
    for (; t + 4 <= s1; t += 4) {
        int sa = eidx[t], sb = eidx[t + 1], sc = eidx[t + 2], sd = eidx[t + 3];
        short8 va = g8[(size_t)sa * 8 + li];
        short8 vb = g8[(size_t)sb * 8 + li];
        short8 vc = g8[(size_t)sc * 8 + li];
        short8 vd = g8[(size_t)sd * 8 + li];
#pragma unroll
        for (int c = 0; c < 8; ++c)
            acc[c] += (b2f(va[c]) + b2f(vb[c])) + (b2f(vc[c]) + b2f(vd[c]));
    }
    for (; t < s1; ++t) {
        int sa = eidx[t];
        short8 va = g8[(size_t)sa * 8 + li];
#pragma unroll
        for (int c = 0; c < 8; ++c) acc[c] += b2f(va[c]);
    }

    const float dn = dinv[node];
    const float4 b0 = reinterpret_cast<const float4*>(bvec)[li * 2];
    const float4 b1 = reinterpret_cast<const float4*>(bvec)[li * 2 + 1];
    float v[8];
    v[0] = acc[0] * dn + b0.x; v[1] = acc[1] * dn + b0.y;
    v[2] = acc[2] * dn + b0.z; v[3] = acc[3] * dn + b0.w;
    v[4] = acc[4] * dn + b1.x; v[5] = acc[5] * dn + b1.y;
    v[6] = acc[6] * dn + b1.z; v[7] = acc[7] * dn + b1.w;

    float m = v[0];
#pragma unroll
    for (int c = 1; c < 8; ++c) m = fmaxf(m, v[c]);
#pragma unroll
    for (int o = 1; o < 8; o <<= 1) m = fmaxf(m, __shfl_xor(m, o));

    float ex = 0.f;
#pragma unroll
    for (int c = 0; c < 8; ++c) ex += __expf(v[c] - m);
#pragma unroll
    for (int o = 1; o < 8; o <<= 1) ex += __shfl_xor(ex, o);
    const float lg = m + __logf(ex);

    float4 r0, r1;
    r0.x = v[0] - lg; r0.y = v[1] - lg; r0.z = v[2] - lg; r0.w = v[3] - lg;
    r1.x = v[4] - lg; r1.y = v[5] - lg; r1.z = v[6] - lg; r1.w = v[7] - lg;
    float4* o4 = reinterpret_cast<float4*>(out + (size_t)node * NCLS);
    o4[li * 2] = r0;
    o4[li * 2 + 1] = r1;
}

extern "C" void kernel_launch(void* const* d_in, const int* in_sizes, int n_in,
                              void* d_out, int out_size, void* d_ws, size_t ws_size,
                              hipStream_t stream) {
    const float* x = (const float*)d_in[0];       // [N, 512]
    const float* W = (const float*)d_in[1];       // [512, 64]
    const float* b = (const float*)d_in[2];       // [64]
    const int* edge_index = (const int*)d_in[3];  // [2, E]

    const int N = in_sizes[0] / F_IN;
    const int E = in_sizes[3] / 2;
    const int* src = edge_index;
    const int* dst = edge_index + E;

    float* out = (float*)d_out;  // [N, 64]

    // workspace layout (16B-aligned pieces first)
    char* ws = (char*)d_ws;
    short* g     = (short*)ws;  ws += (size_t)N * NCLS * 2;          // 12.8 MB bf16
    short* Wb    = (short*)ws;  ws += 4096 * 16;                     // 64 KB
    float* dinv  = (float*)ws;  ws += (size_t)N * 4;
    int*   cnt   = (int*)ws;    ws += (size_t)N * CNT_STRIDE * 4;    // 6.4 MB line-padded
    int*   off   = (int*)ws;    ws += (size_t)(N + 4) * 4;
    int*   parts = (int*)ws;    ws += 1024 * 4;
    unsigned short* rank = (unsigned short*)ws;  ws += (size_t)((E + 7) & ~7) * 2;
    int*   eidx  = (int*)ws;    // E ints

    const int nWords = N * CNT_STRIDE;
    const int nScanBlocks = (N + SCAN_BLK - 1) / SCAN_BLK;
    const int fillBlocks = (E + 1023) / 1024;
    const int degBlocks = (E + 2047) / 2048;

    k_prelude<<<16 + (nWords / 4 + 255) / 256, 256, 0, stream>>>(W, Wb, cnt, nWords);

    k_deg<<<degBlocks, 256, 0, stream>>>(dst, cnt, rank, E);

    k_scan1<<<nScanBlocks, SCAN_BLK, 0, stream>>>(cnt, off, parts, dinv, N);
    k_scan2<<<1, 256, 0, stream>>>(parts, nScanBlocks);

    k_gemm<<<(N + 127) / 128, 256, 0, stream>>>(x, Wb, dinv, g, N);

    k_fill<<<fillBlocks, 256, 0, stream>>>(src, dst, off, parts, rank, eidx, E);

    k_agg<<<(N + 31) / 32, 256, 0, stream>>>(g, dinv, b, off, parts, eidx, out, N);
}